// Round 9
// baseline (451.066 us; speedup 1.0000x reference)
//
#include <hip/hip_runtime.h>
#include <hip/hip_bf16.h>
#include <math.h>

// Suffix-max scan along H (reverse), NCHW: x[8,128,256,256] f32.
// out[n,c,h,w] = max_{j>=h} x[n,c,j,w].
//
// R9: contiguous-ASCENDING per-wave streams (the last untested cell).
// R3 = contiguous but descending; R8 = ascending but 256B-strided; the
// 6.3-6.5 TB/s references (copy/fill) are contiguous ascending. Here:
// block = 1024 thr = 16 waves = one slab; wave w owns rows 16w..16w+15
// (contiguous 16 KiB); lane owns float4 -> each load/store is a full
// 1 KiB row and consecutive i are address-consecutive. Loads ascending
// & independent; suffix-max in registers; cross-wave combine via LDS;
// stores ascending. Traffic optimal: 256 MiB read + 256 MiB write.

#define H 256
#define W 256
#define CH 16          // rows per wave
#define NW 16          // waves per block (= chunks per slab)
#define RS (W / 4)     // row stride in f32x4 = 64

typedef float f32x4 __attribute__((ext_vector_type(4)));

__device__ __forceinline__ f32x4 max4(f32x4 a, f32x4 b) {
    f32x4 r;
    r.x = fmaxf(a.x, b.x);
    r.y = fmaxf(a.y, b.y);
    r.z = fmaxf(a.z, b.z);
    r.w = fmaxf(a.w, b.w);
    return r;
}

__global__ __launch_bounds__(1024, 8) void VerticalLinePool_kernel(
    const float* __restrict__ x, float* __restrict__ out) {
    const int lane = threadIdx.x & 63;   // f32x4 slot within row
    const int wv   = threadIdx.x >> 6;   // wave = chunk 0..15
    const int slab = blockIdx.x;         // (n,c) 0..1023

    const size_t base = (size_t)slab * (H * W) + (size_t)(wv * CH) * W + (size_t)lane * 4;
    const f32x4* __restrict__ xp = (const f32x4*)(x + base);
    f32x4* __restrict__ op = (f32x4*)(out + base);

    // Phase 1a: ascending, independent, contiguous loads (16 KiB/wave).
    f32x4 s[CH];
#pragma unroll
    for (int i = 0; i < CH; ++i) {
        s[i] = xp[(size_t)i * RS];
    }

    // Phase 1b: in-register suffix-max (backward, no memory ops).
    f32x4 run = (f32x4)(-INFINITY);
#pragma unroll
    for (int i = CH - 1; i >= 0; --i) {
        run = max4(run, s[i]);
        s[i] = run;
    }

    // Cross-wave combine: wave wv needs max of chunk totals wv+1..15.
    __shared__ f32x4 tot[NW][64];
    tot[wv][lane] = run;
    __syncthreads();

    f32x4 M = (f32x4)(-INFINITY);        // loop bounds wave-uniform
    for (int k = wv + 1; k < NW; ++k)
        M = max4(M, tot[k][lane]);

    // Phase 2: ascending contiguous stores.
#pragma unroll
    for (int i = 0; i < CH; ++i) {
        op[(size_t)i * RS] = max4(s[i], M);
    }
}

extern "C" void kernel_launch(void* const* d_in, const int* in_sizes, int n_in,
                              void* d_out, int out_size, void* d_ws, size_t ws_size,
                              hipStream_t stream) {
    const float* x = (const float*)d_in[0];
    float* out = (float*)d_out;
    const int slabs = in_sizes[0] / (H * W);   // 8*128 = 1024
    VerticalLinePool_kernel<<<slabs, 1024, 0, stream>>>(x, out);
}